// Round 6
// baseline (283.060 us; speedup 1.0000x reference)
//
#include <hip/hip_runtime.h>

// ============================================================================
// Piecewise-constant LUT formulation of the 16-step SNN scan.
//
// Reference per element (fp32, verified bit-exact in R0-R4):
//   a = |x|; v = a; z = 0; acc = 0
//   for t in 0..15: v = fmaf(-z,h[t],v); z = (v > T[t]); acc = fmaf(z,d[t],acc)
//   out = acc * sign(x)
//
// Key facts:
//  - Within a fixed firing pattern, v_t(a) is monotone nondecreasing in a
//    (composition of fl(v - const)), so each z_t flips at most once per
//    segment -> f(a) is a step function of a.
//  - acc depends ONLY on the firing pattern (z,d constants), so the value is
//    EXACTLY constant per segment.
//  - Breakpoints are found by binary search in fp32 BIT space running the
//    true fmaf chain -> exact, no epsilon.
//
// K1 (1 block, 1024 thr): interval refinement (16 rounds) -> segments;
// bitonic-sort breakpoints; per-segment exact value; 2048-bin index grid.
// Writes table to d_ws (~12.3 KB).
// K2 (2048 x 256): stream x, per element: bin -> grid start -> short walk
// over breakpoints in LDS -> value, sign via xor. Fallback to direct scan
// if table overflowed (or host falls back if ws too small).
// ============================================================================

#define NSEG_MAX 512
#define NBIN 2048
// ws layout (uint words):
// [0]=nseg  [1]=overflow  [2..2+512)=sorted segment-start bits
// [514..514+512)=segment values (float bits)  [1026..1026+2048)=grid start idx
#define WS_WORDS (2 + NSEG_MAX + NSEG_MAX + NBIN)

__device__ __forceinline__ int predmask(float a, const float* __restrict__ hh,
                                        const float* __restrict__ TT) {
    float v = a, z = 0.0f;
    int m = 0;
#pragma unroll
    for (int k = 0; k < 16; ++k) {
        v = fmaf(-z, hh[k], v);
        int zb = (v > TT[k]) ? 1 : 0;
        z = zb ? 1.0f : 0.0f;
        m |= zb << k;
    }
    return m;
}

__device__ __forceinline__ float scan_val(float a, const float* __restrict__ hh,
                                          const float* __restrict__ dd,
                                          const float* __restrict__ TT) {
    float v = a, z = 0.0f, acc = 0.0f;
#pragma unroll
    for (int k = 0; k < 16; ++k) {
        v = fmaf(-z, hh[k], v);
        z = (v > TT[k]) ? 1.0f : 0.0f;
        acc = fmaf(z, dd[k], acc);
    }
    return acc;
}

// ---------------------------------------------------------------- K1: build
__global__ __launch_bounds__(1024) void snn_build_lut(
    const float* __restrict__ h, const float* __restrict__ d,
    const float* __restrict__ T, unsigned int* __restrict__ ws) {
    __shared__ unsigned int segL[NSEG_MAX], segH[NSEG_MAX];
    __shared__ int nseg, ovf;
    const int tid = threadIdx.x;
    const int NT = blockDim.x;

    float hh[16], dd[16], TT[16];
#pragma unroll
    for (int k = 0; k < 16; ++k) { hh[k] = h[k]; dd[k] = d[k]; TT[k] = T[k]; }

    if (tid == 0) { segL[0] = 0u; segH[0] = 0x7F800000u; nseg = 1; ovf = 0; }
    __syncthreads();

    // 16 refinement rounds: after round t every segment has uniform z_{0..t}.
    for (int t = 0; t < 16; ++t) {
        int cnt = nseg;
        __syncthreads();
        for (int i = tid; i < cnt; i += NT) {
            unsigned int L = segL[i], H = segH[i];
            int pL = (predmask(__uint_as_float(L), hh, TT) >> t) & 1;
            int pH = (predmask(__uint_as_float(H - 1u), hh, TT) >> t) & 1;
            if (pL != pH) {  // monotone: pL=0, pH=1. find first-true bit a*.
                unsigned int lo = L, hi = H - 1u;  // pred(hi)==1
                while (hi - lo > 2u) {             // 4-ary search (3 probes ILP)
                    unsigned int q = (hi - lo) >> 2;
                    unsigned int m1 = lo + q, m2 = lo + 2u * q, m3 = lo + 3u * q;
                    int p1 = (predmask(__uint_as_float(m1), hh, TT) >> t) & 1;
                    int p2 = (predmask(__uint_as_float(m2), hh, TT) >> t) & 1;
                    int p3 = (predmask(__uint_as_float(m3), hh, TT) >> t) & 1;
                    if (p1) hi = m1;
                    else if (p2) { lo = m1 + 1u; hi = m2; }
                    else if (p3) { lo = m2 + 1u; hi = m3; }
                    else lo = m3 + 1u;
                }
                while (lo < hi) {
                    if ((predmask(__uint_as_float(lo), hh, TT) >> t) & 1) break;
                    ++lo;
                }
                unsigned int astar = lo;  // first a with z_t = 1;  L < astar <= H-1
                int k = atomicAdd(&nseg, 1);
                if (k < NSEG_MAX) {
                    segL[k] = astar;
                    segH[k] = H;
                    segH[i] = astar;
                } else {
                    ovf = 1;
                }
            }
        }
        __syncthreads();
    }

    int ns = (nseg > NSEG_MAX) ? NSEG_MAX : nseg;
    for (int i = tid; i < NSEG_MAX; i += NT)
        if (i >= ns) segL[i] = 0xFFFFFFFFu;  // sort padding
    __syncthreads();

    // bitonic sort of segL[0..512) ascending (uint == positive-float order)
    for (int k = 2; k <= NSEG_MAX; k <<= 1) {
        for (int s = k >> 1; s > 0; s >>= 1) {
            __syncthreads();
            if (tid < NSEG_MAX / 2) {
                int idx = ((tid / s) * (s << 1)) + (tid % s);
                int part = idx | s;
                bool up = ((idx & k) == 0);
                unsigned int A = segL[idx], B = segL[part];
                if (up ? (A > B) : (A < B)) { segL[idx] = B; segL[part] = A; }
            }
        }
    }
    __syncthreads();

    // per-segment exact value (constant across the segment: acc depends only
    // on the firing pattern) — evaluate the true chain at the segment start.
    for (int j = tid; j < ns; j += NT)
        ws[2 + NSEG_MAX + j] =
            __float_as_uint(scan_val(__uint_as_float(segL[j]), hh, dd, TT));

    // grid: gs[b] = largest j with segL[j] <= bits(b/NBIN)   (segL[0]=0)
    for (int b = tid; b < NBIN; b += NT) {
        float blo = (float)b * (1.0f / (float)NBIN);
        unsigned int tb = __float_as_uint(blo);
        int lo = 0, hi = ns - 1, j = 0;
        while (lo <= hi) {
            int mid = (lo + hi) >> 1;
            if (segL[mid] <= tb) { j = mid; lo = mid + 1; }
            else hi = mid - 1;
        }
        ws[2 + 2 * NSEG_MAX + b] = (unsigned int)j;
    }
    for (int i = tid; i < NSEG_MAX; i += NT) ws[2 + i] = segL[i];
    if (tid == 0) { ws[0] = (unsigned int)ns; ws[1] = (unsigned int)ovf; }
}

// ---------------------------------------------------------------- K2: apply
__device__ __forceinline__ float lut_elem(float xe, const unsigned int* bpS,
                                          const float* valS,
                                          const unsigned short* gsS, int ns,
                                          bool ovf, const float* __restrict__ hh,
                                          const float* __restrict__ dd,
                                          const float* __restrict__ TT) {
    unsigned int sb = __float_as_uint(xe) & 0x80000000u;
    float r;
    if (!ovf) {
        unsigned int ab = __float_as_uint(xe) & 0x7FFFFFFFu;
        float a = __uint_as_float(ab);
        float as = fminf(a * (float)NBIN, (float)(NBIN - 1));
        int b = (int)as;
        int j = gsS[b];
        while (j + 1 < ns && ab >= bpS[j + 1]) ++j;
        r = valS[j];
    } else {
        r = scan_val(__uint_as_float(__float_as_uint(xe) & 0x7FFFFFFFu), hh, dd, TT);
    }
    float o = __uint_as_float(__float_as_uint(r) ^ sb);
    return (xe == 0.0f) ? 0.0f : o;
}

__global__ __launch_bounds__(256) void snn_apply(
    const float* __restrict__ x, const float* __restrict__ h,
    const float* __restrict__ d, const float* __restrict__ T,
    float* __restrict__ out, const unsigned int* __restrict__ ws,
    int n8, int n4, int n) {
    __shared__ unsigned int bpS[NSEG_MAX];
    __shared__ float valS[NSEG_MAX];
    __shared__ unsigned short gsS[NBIN];
    __shared__ int nsS, ovfS;
    const int tid = threadIdx.x;

    float hh[16], dd[16], TT[16];  // wave-uniform -> SGPR; used by fallback only
#pragma unroll
    for (int k = 0; k < 16; ++k) { hh[k] = h[k]; dd[k] = d[k]; TT[k] = T[k]; }

    for (int i = tid; i < NSEG_MAX; i += 256) {
        bpS[i] = ws[2 + i];
        valS[i] = __uint_as_float(ws[2 + NSEG_MAX + i]);
    }
    for (int b = tid; b < NBIN; b += 256)
        gsS[b] = (unsigned short)ws[2 + 2 * NSEG_MAX + b];
    if (tid == 0) { nsS = (int)ws[0]; ovfS = (int)ws[1]; }
    __syncthreads();
    const int ns = nsS;
    const bool ovf = (ovfS != 0);

    const float4* __restrict__ x4 = reinterpret_cast<const float4*>(x);
    float4* __restrict__ o4 = reinterpret_cast<float4*>(out);
    const int gtid = blockIdx.x * blockDim.x + tid;
    const int nt = gridDim.x * blockDim.x;

#define APPLY4(vv)                                                              \
    {                                                                           \
        float4 ov;                                                              \
        ov.x = lut_elem(vv.x, bpS, valS, gsS, ns, ovf, hh, dd, TT);             \
        ov.y = lut_elem(vv.y, bpS, valS, gsS, ns, ovf, hh, dd, TT);             \
        ov.z = lut_elem(vv.z, bpS, valS, gsS, ns, ovf, hh, dd, TT);             \
        ov.w = lut_elem(vv.w, bpS, valS, gsS, ns, ovf, hh, dd, TT);             \
        vv = ov;                                                                \
    }

    int i = gtid;  // unit = pair of adjacent float4 (R4 structure)
    if (i < n8) {
        float4 ca = x4[2 * i], cb = x4[2 * i + 1];
        int nx = i + nt;
        while (nx < n8) {
            float4 pa = x4[2 * nx], pb = x4[2 * nx + 1];
            APPLY4(ca); APPLY4(cb);
            o4[2 * i] = ca; o4[2 * i + 1] = cb;
            ca = pa; cb = pb;
            i = nx; nx += nt;
        }
        APPLY4(ca); APPLY4(cb);
        o4[2 * i] = ca; o4[2 * i + 1] = cb;
    }
    for (int j = n8 * 2 + gtid; j < n4; j += nt) {
        float4 v = x4[j];
        APPLY4(v);
        o4[j] = v;
    }
    for (int j = n4 * 4 + gtid; j < n; j += nt)
        out[j] = lut_elem(x[j], bpS, valS, gsS, ns, ovf, hh, dd, TT);
#undef APPLY4
}

// ------------------------------------------------- direct fallback (tiny ws)
__global__ __launch_bounds__(256) void snn_direct(
    const float* __restrict__ x, const float* __restrict__ h,
    const float* __restrict__ d, const float* __restrict__ T,
    float* __restrict__ out, int n4, int n) {
    float hh[16], dd[16], TT[16];
#pragma unroll
    for (int k = 0; k < 16; ++k) { hh[k] = h[k]; dd[k] = d[k]; TT[k] = T[k]; }
    const float4* __restrict__ x4 = reinterpret_cast<const float4*>(x);
    float4* __restrict__ o4 = reinterpret_cast<float4*>(out);
    const int gtid = blockIdx.x * blockDim.x + threadIdx.x;
    const int nt = gridDim.x * blockDim.x;
    for (int i = gtid; i < n4; i += nt) {
        float4 v = x4[i], ov;
        float* pi = &v.x;
        float* po = &ov.x;
#pragma unroll
        for (int e = 0; e < 4; ++e) {
            float xe = pi[e];
            float acc = scan_val(fabsf(xe), hh, dd, TT);
            unsigned int rb =
                __float_as_uint(acc) ^ (__float_as_uint(xe) & 0x80000000u);
            po[e] = (xe == 0.0f) ? 0.0f : __uint_as_float(rb);
        }
        o4[i] = ov;
    }
    for (int j = n4 * 4 + gtid; j < n; j += nt) {
        float xe = x[j];
        float acc = scan_val(fabsf(xe), hh, dd, TT);
        unsigned int rb = __float_as_uint(acc) ^ (__float_as_uint(xe) & 0x80000000u);
        out[j] = (xe == 0.0f) ? 0.0f : __uint_as_float(rb);
    }
}

extern "C" void kernel_launch(void* const* d_in, const int* in_sizes, int n_in,
                              void* d_out, int out_size, void* d_ws, size_t ws_size,
                              hipStream_t stream) {
    const float* x = (const float*)d_in[0];
    const float* h = (const float*)d_in[1];
    const float* d = (const float*)d_in[2];
    const float* T = (const float*)d_in[3];
    float* out = (float*)d_out;

    const int n = in_sizes[0];
    const int n4 = n / 4;
    const int n8 = n / 8;

    if (ws_size < (size_t)WS_WORDS * 4) {  // no room for the table: direct path
        int grid = 2048;
        const int needed = (n4 + 255) / 256;
        if (grid > needed) grid = needed > 0 ? needed : 1;
        snn_direct<<<grid, 256, 0, stream>>>(x, h, d, T, out, n4, n);
        return;
    }

    unsigned int* ws = (unsigned int*)d_ws;
    snn_build_lut<<<1, 1024, 0, stream>>>(h, d, T, ws);

    int grid = 2048;
    const int needed = (n8 + 255) / 256;
    if (grid > needed) grid = needed > 0 ? needed : 1;
    snn_apply<<<grid, 256, 0, stream>>>(x, h, d, T, out, ws, n8, n4, n);
}

// Round 7
// 155.925 us; speedup vs baseline: 1.8154x; 1.8154x over previous
//
#include <hip/hip_runtime.h>

// ============================================================================
// Piecewise-constant LUT, v2: parallel build + single-gather apply.
//
// Reference per element (fp32; bit-exact chain validated R0-R5):
//   a = |x|; v = a; z = 0; acc = 0
//   for t: v = fmaf(-z,h[t],v); z = (v > T[t]); acc = fmaf(z,d[t],acc)
//   out = acc * sign(x)
//
// THEOREM (endpoint-mask rule): if predmask(A)==predmask(B) on [A,B] (bit
// space of nonneg fp32), the mask is constant on [A,B]. Induction: with
// z_{0..t-1} constant, v_t = fl(v_{t-1} - const) is monotone in a (IEEE
// rounding monotone), so z_t is monotone; equal endpoints => constant.
// => build is per-bin independent: 2 predmask evals/bin; binary searches
// only in bins whose endpoint masks differ (each search's left part is
// proven uniform by the same rule => complete breakpoint enumeration).
// acc depends only on the mask => exact per-segment value.
//
// Bins: 4096 x 9216 ULPs over bit-range [0.0625, 1.5]; low/high regions
// verified uniform at build (else tagged for exact scan). Bins with 1-2
// breakpoints get side entries (branchless 3-way select); >=3 (never seen)
// -> exact-scan tag.
// ============================================================================

#define BIN_B0 0x3D800000u   // bits(0.0625)
#define BIN_B1 0x3FC00000u   // bits(1.5)
#define BIN_RANGE 0x02400000u
#define NBIN 4096
#define BIN_STEP 9216u       // BIN_RANGE / NBIN exactly
#define NSIDE_MAX 512
#define SCANTAG 0xFFC00000u

#define W_NSIDE 0
#define W_LO 1
#define W_HI 2
#define W_LUT 16
#define W_BP (W_LUT + NBIN)              // uint2 per side entry
#define W_VAL (W_BP + 2 * NSIDE_MAX)     // 4 floats per side entry
#define WS_WORDS (W_VAL + 4 * NSIDE_MAX) // 7184 words = 28736 B

__device__ __forceinline__ int predmask16(float a, const float* __restrict__ hh,
                                          const float* __restrict__ TT) {
    float v = a, z = 0.0f;
    int m = 0;
#pragma unroll
    for (int k = 0; k < 16; ++k) {
        v = fmaf(-z, hh[k], v);
        int zb = (v > TT[k]) ? 1 : 0;
        z = zb ? 1.0f : 0.0f;
        m |= zb << k;
    }
    return m;
}

__device__ __forceinline__ unsigned int valbits(int m, const float* __restrict__ dd) {
    // acc chain: fmaf(1,d,acc)=fl(acc+d); fmaf(0,d,acc)=acc exactly.
    float acc = 0.0f;
#pragma unroll
    for (int k = 0; k < 16; ++k)
        acc = ((m >> k) & 1) ? (acc + dd[k]) : acc;
    return __float_as_uint(acc);
}

__device__ __forceinline__ float scan_exact(unsigned int ab, const float* __restrict__ h,
                                            const float* __restrict__ d,
                                            const float* __restrict__ T) {
    float v = __uint_as_float(ab), z = 0.0f, acc = 0.0f;
#pragma unroll
    for (int k = 0; k < 16; ++k) {
        v = fmaf(-z, h[k], v);
        z = (v > T[k]) ? 1.0f : 0.0f;
        acc = fmaf(z, d[k], acc);
    }
    return acc;
}

// ---------------------------------------------------------------- K1: build
__global__ __launch_bounds__(1024) void snn_build(
    const float* __restrict__ h, const float* __restrict__ d,
    const float* __restrict__ T, unsigned int* __restrict__ ws) {
    const int tid = threadIdx.x;
    float hh[16], dd[16], TT[16];
#pragma unroll
    for (int k = 0; k < 16; ++k) { hh[k] = h[k]; dd[k] = d[k]; TT[k] = T[k]; }

    if (tid == 0) ws[W_NSIDE] = 0u;
    __syncthreads();  // single block: counter init ordered before atomics

    for (int u = tid; u < NBIN + 2; u += 1024) {
        if (u == NBIN) {  // low region [0, B0-1]
            int mA = predmask16(__uint_as_float(0u), hh, TT);
            int mB = predmask16(__uint_as_float(BIN_B0 - 1u), hh, TT);
            ws[W_LO] = (mA == mB) ? valbits(mA, dd) : SCANTAG;
            continue;
        }
        if (u == NBIN + 1) {  // high region [B1, max finite]
            int mA = predmask16(__uint_as_float(BIN_B1), hh, TT);
            int mB = predmask16(__uint_as_float(0x7F7FFFFFu), hh, TT);
            ws[W_HI] = (mA == mB) ? valbits(mA, dd) : SCANTAG;
            continue;
        }
        const unsigned int Lb = BIN_B0 + (unsigned int)u * BIN_STEP;
        const unsigned int Hb = Lb + (BIN_STEP - 1u);
        int mL = predmask16(__uint_as_float(Lb), hh, TT);
        int mH = predmask16(__uint_as_float(Hb), hh, TT);
        if (mL == mH) { ws[W_LUT + u] = valbits(mL, dd); continue; }

        // first transition p1 in (Lb, Hb]; left part proven uniform.
        unsigned int lo = Lb, hi = Hb;
        int mhi = mH;
        while (hi - lo > 1u) {
            unsigned int mid = lo + ((hi - lo) >> 1);
            int mm = predmask16(__uint_as_float(mid), hh, TT);
            if (mm == mL) lo = mid; else { hi = mid; mhi = mm; }
        }
        unsigned int p1 = hi;
        int m1 = mhi;

        unsigned int p2 = 0xFFFFFFFFu;
        int m2 = m1;
        bool ok = true;
        if (m1 != mH) {  // second transition
            lo = p1; hi = Hb; mhi = mH;
            while (hi - lo > 1u) {
                unsigned int mid = lo + ((hi - lo) >> 1);
                int mm = predmask16(__uint_as_float(mid), hh, TT);
                if (mm == m1) lo = mid; else { hi = mid; mhi = mm; }
            }
            p2 = hi;
            m2 = mhi;
            ok = (m2 == mH);  // else >=3 transitions in this bin
        }
        if (ok) {
            int idx = atomicAdd((int*)&ws[W_NSIDE], 1);
            if (idx < NSIDE_MAX) {
                ws[W_BP + 2 * idx] = p1;
                ws[W_BP + 2 * idx + 1] = p2;
                ws[W_VAL + 4 * idx + 0] = valbits(mL, dd);
                ws[W_VAL + 4 * idx + 1] = valbits(m1, dd);
                ws[W_VAL + 4 * idx + 2] = valbits(m2, dd);
                ws[W_VAL + 4 * idx + 3] = 0u;
                ws[W_LUT + u] = 0x7F800000u | (unsigned int)idx;
            } else {
                ws[W_LUT + u] = SCANTAG;
            }
        } else {
            ws[W_LUT + u] = SCANTAG;
        }
    }
}

// ---------------------------------------------------------------- K2: apply
__device__ __forceinline__ float lut_elem(float xe, const unsigned int* __restrict__ lutS,
                                          const uint2* __restrict__ bpS,
                                          const float* __restrict__ valS,
                                          unsigned int lo_e, unsigned int hi_e,
                                          const float* __restrict__ h,
                                          const float* __restrict__ d,
                                          const float* __restrict__ T) {
    const unsigned int u = __float_as_uint(xe);
    const unsigned int sb = u & 0x80000000u;
    const unsigned int ab = u & 0x7FFFFFFFu;
    unsigned int t = ab - BIN_B0;                       // wraps if ab < B0
    if (t > BIN_RANGE - 1u) t = BIN_RANGE - 1u;         // clamp wrap / high
    const unsigned int bin = ((t >> 10) * 58255u) >> 19;  // exact /9216
    unsigned int eb = lutS[bin];
    eb = (ab < BIN_B0) ? lo_e : eb;
    eb = (ab >= BIN_B1) ? hi_e : eb;
    if (__builtin_expect((eb & 0x7F800000u) == 0x7F800000u, 0)) {
        if (eb != SCANTAG) {
            const unsigned int idx = eb & 0x3FFFFFu;
            const uint2 bp = bpS[idx];
            const unsigned int j = (ab >= bp.x ? 1u : 0u) + (ab >= bp.y ? 1u : 0u);
            eb = __float_as_uint(valS[4u * idx + j]);
        } else {
            eb = __float_as_uint(scan_exact(ab, h, d, T));  // cold exact path
        }
    }
    const float r = __uint_as_float(eb ^ sb);
    return (xe == 0.0f) ? 0.0f : r;
}

__global__ __launch_bounds__(256) void snn_apply(
    const float* __restrict__ x, const float* __restrict__ h,
    const float* __restrict__ d, const float* __restrict__ T,
    float* __restrict__ out, const unsigned int* __restrict__ ws,
    int n8, int n4, int n) {
    __shared__ unsigned int lutS[NBIN];
    __shared__ uint2 bpS[NSIDE_MAX];
    __shared__ float valS[4 * NSIDE_MAX];
    const int tid = threadIdx.x;

    for (int i = tid; i < NBIN; i += 256) lutS[i] = ws[W_LUT + i];
    for (int i = tid; i < NSIDE_MAX; i += 256) {
        bpS[i].x = ws[W_BP + 2 * i];
        bpS[i].y = ws[W_BP + 2 * i + 1];
    }
    for (int i = tid; i < 4 * NSIDE_MAX; i += 256)
        valS[i] = __uint_as_float(ws[W_VAL + i]);
    const unsigned int lo_e = ws[W_LO];
    const unsigned int hi_e = ws[W_HI];
    __syncthreads();

    const float4* __restrict__ x4 = reinterpret_cast<const float4*>(x);
    float4* __restrict__ o4 = reinterpret_cast<float4*>(out);
    const int gtid = blockIdx.x * blockDim.x + tid;
    const int nt = gridDim.x * blockDim.x;

#define APPLY4(vv)                                                             \
    {                                                                          \
        float4 ov;                                                             \
        ov.x = lut_elem(vv.x, lutS, bpS, valS, lo_e, hi_e, h, d, T);           \
        ov.y = lut_elem(vv.y, lutS, bpS, valS, lo_e, hi_e, h, d, T);           \
        ov.z = lut_elem(vv.z, lutS, bpS, valS, lo_e, hi_e, h, d, T);           \
        ov.w = lut_elem(vv.w, lutS, bpS, valS, lo_e, hi_e, h, d, T);           \
        vv = ov;                                                               \
    }

    int i = gtid;  // unit = pair of adjacent float4 (R4 skeleton)
    if (i < n8) {
        float4 ca = x4[2 * i], cb = x4[2 * i + 1];
        int nx = i + nt;
        while (nx < n8) {
            float4 pa = x4[2 * nx], pb = x4[2 * nx + 1];
            APPLY4(ca); APPLY4(cb);
            o4[2 * i] = ca; o4[2 * i + 1] = cb;
            ca = pa; cb = pb;
            i = nx; nx += nt;
        }
        APPLY4(ca); APPLY4(cb);
        o4[2 * i] = ca; o4[2 * i + 1] = cb;
    }
    for (int j = n8 * 2 + gtid; j < n4; j += nt) {
        float4 v = x4[j];
        APPLY4(v);
        o4[j] = v;
    }
    for (int j = n4 * 4 + gtid; j < n; j += nt)
        out[j] = lut_elem(x[j], lutS, bpS, valS, lo_e, hi_e, h, d, T);
#undef APPLY4
}

// -------------------------------------------- direct fallback (ws too small)
__global__ __launch_bounds__(256) void snn_direct(
    const float* __restrict__ x, const float* __restrict__ h,
    const float* __restrict__ d, const float* __restrict__ T,
    float* __restrict__ out, int n4, int n) {
    float hh[16], dd[16], TT[16];
#pragma unroll
    for (int k = 0; k < 16; ++k) { hh[k] = h[k]; dd[k] = d[k]; TT[k] = T[k]; }
    const float4* __restrict__ x4 = reinterpret_cast<const float4*>(x);
    float4* __restrict__ o4 = reinterpret_cast<float4*>(out);
    const int gtid = blockIdx.x * blockDim.x + threadIdx.x;
    const int nt = gridDim.x * blockDim.x;
    for (int i = gtid; i < n4; i += nt) {
        float4 v = x4[i], ov;
        float* pi = &v.x;
        float* po = &ov.x;
#pragma unroll
        for (int e = 0; e < 4; ++e) {
            float xe = pi[e];
            float acc = scan_exact(__float_as_uint(xe) & 0x7FFFFFFFu, hh, dd, TT);
            unsigned int rb =
                __float_as_uint(acc) ^ (__float_as_uint(xe) & 0x80000000u);
            po[e] = (xe == 0.0f) ? 0.0f : __uint_as_float(rb);
        }
        o4[i] = ov;
    }
    for (int j = n4 * 4 + gtid; j < n; j += nt) {
        float xe = x[j];
        float acc = scan_exact(__float_as_uint(xe) & 0x7FFFFFFFu, hh, dd, TT);
        unsigned int rb = __float_as_uint(acc) ^ (__float_as_uint(xe) & 0x80000000u);
        out[j] = (xe == 0.0f) ? 0.0f : __uint_as_float(rb);
    }
}

extern "C" void kernel_launch(void* const* d_in, const int* in_sizes, int n_in,
                              void* d_out, int out_size, void* d_ws, size_t ws_size,
                              hipStream_t stream) {
    const float* x = (const float*)d_in[0];
    const float* h = (const float*)d_in[1];
    const float* d = (const float*)d_in[2];
    const float* T = (const float*)d_in[3];
    float* out = (float*)d_out;

    const int n = in_sizes[0];
    const int n4 = n / 4;
    const int n8 = n / 8;

    if (ws_size < (size_t)WS_WORDS * 4) {
        int grid = 2048;
        const int needed = (n4 + 255) / 256;
        if (grid > needed) grid = needed > 0 ? needed : 1;
        snn_direct<<<grid, 256, 0, stream>>>(x, h, d, T, out, n4, n);
        return;
    }

    unsigned int* ws = (unsigned int*)d_ws;
    snn_build<<<1, 1024, 0, stream>>>(h, d, T, ws);

    // 28.7 KB LDS/block -> 5 blocks/CU -> 1280 blocks fills the chip.
    int grid = 1280;
    const int needed = (n8 + 255) / 256;
    if (grid > needed) grid = needed > 0 ? needed : 1;
    snn_apply<<<grid, 256, 0, stream>>>(x, h, d, T, out, ws, n8, n4, n);
}

// Round 8
// 142.391 us; speedup vs baseline: 1.9879x; 1.0950x over previous
//
#include <hip/hip_runtime.h>

// ============================================================================
// Piecewise-constant LUT, v3: multi-block build + single-read side entries.
//
// Reference per element (fp32; chain validated bit-exact R0-R6):
//   a = |x|; v = a; z = 0; acc = 0
//   for t: v = fmaf(-z,h[t],v); z = (v > T[t]); acc = fmaf(z,d[t],acc)
//   out = acc * sign(x)
//
// Endpoint-mask rule (R6): equal 16-bit predicate masks at interval endpoints
// => mask constant on the interval (per-bit monotone under uniform prefix).
// Value depends only on the mask => exact per-segment value.
//
// Bins: 4096 x 9216 ULPs over [0.0625, 1.5] bit-space. Clean bin -> value
// inline in LUT. Bin with 1-2 transitions -> 16B side entry
// {u16 off1, u16 off2, v0, v1, v2} read with ONE ds_read_b128.
// >=3 transitions / overflow -> SCANTAG (exact per-element scan, cold).
// ============================================================================

#define BIN_B0 0x3D800000u   // bits(0.0625)
#define BIN_B1 0x3FC00000u   // bits(1.5)
#define BIN_RANGE 0x02400000u
#define NBIN 4096
#define BIN_STEP 9216u
#define NSIDE_MAX 512
#define SCANTAG 0xFFC00000u

#define W_NSIDE 0
#define W_LO 1
#define W_HI 2
#define W_LUT 4
#define W_SIDE (W_LUT + NBIN)            // uint4 per entry
#define WS_WORDS (W_SIDE + 4 * NSIDE_MAX)  // 6148 words = 24.6 KB

__device__ __forceinline__ int predmask16(float a, const float* __restrict__ hh,
                                          const float* __restrict__ TT) {
    float v = a, z = 0.0f;
    int m = 0;
#pragma unroll
    for (int k = 0; k < 16; ++k) {
        v = fmaf(-z, hh[k], v);
        int zb = (v > TT[k]) ? 1 : 0;
        z = zb ? 1.0f : 0.0f;
        m |= zb << k;
    }
    return m;
}

__device__ __forceinline__ unsigned int valbits(int m, const float* __restrict__ dd) {
    float acc = 0.0f;
#pragma unroll
    for (int k = 0; k < 16; ++k)
        acc = ((m >> k) & 1) ? (acc + dd[k]) : acc;  // fl(acc+d) == fmaf(1,d,acc)
    return __float_as_uint(acc);
}

__device__ __forceinline__ float scan_exact(unsigned int ab, const float* __restrict__ hh,
                                            const float* __restrict__ dd,
                                            const float* __restrict__ TT) {
    float v = __uint_as_float(ab), z = 0.0f, acc = 0.0f;
#pragma unroll
    for (int k = 0; k < 16; ++k) {
        v = fmaf(-z, hh[k], v);
        z = (v > TT[k]) ? 1.0f : 0.0f;
        acc = fmaf(z, dd[k], acc);
    }
    return acc;
}

// ---------------------------------------------------------------- K1: build
__global__ __launch_bounds__(256) void snn_build(
    const float* __restrict__ h, const float* __restrict__ d,
    const float* __restrict__ T, unsigned int* __restrict__ ws) {
    const int u = blockIdx.x * 256 + threadIdx.x;
    if (u >= NBIN + 2) return;
    float hh[16], dd[16], TT[16];
#pragma unroll
    for (int k = 0; k < 16; ++k) { hh[k] = h[k]; dd[k] = d[k]; TT[k] = T[k]; }

    if (u == NBIN) {  // low region [0, B0)
        int mA = predmask16(__uint_as_float(0u), hh, TT);
        int mB = predmask16(__uint_as_float(BIN_B0 - 1u), hh, TT);
        ws[W_LO] = (mA == mB) ? valbits(mA, dd) : SCANTAG;
        return;
    }
    if (u == NBIN + 1) {  // high region [B1, max finite]
        int mA = predmask16(__uint_as_float(BIN_B1), hh, TT);
        int mB = predmask16(__uint_as_float(0x7F7FFFFFu), hh, TT);
        ws[W_HI] = (mA == mB) ? valbits(mA, dd) : SCANTAG;
        return;
    }

    const unsigned int Lb = BIN_B0 + (unsigned int)u * BIN_STEP;
    const unsigned int Hb = Lb + (BIN_STEP - 1u);
    const int mL = predmask16(__uint_as_float(Lb), hh, TT);
    const int mH = predmask16(__uint_as_float(Hb), hh, TT);
    if (mL == mH) { ws[W_LUT + u] = valbits(mL, dd); return; }

    // first transition p1 in (Lb, Hb]
    unsigned int lo = Lb, hi = Hb;
    int mhi = mH;
    while (hi - lo > 1u) {
        unsigned int mid = lo + ((hi - lo) >> 1);
        int mm = predmask16(__uint_as_float(mid), hh, TT);
        if (mm == mL) lo = mid; else { hi = mid; mhi = mm; }
    }
    const unsigned int p1 = hi;
    const int m1 = mhi;

    unsigned int p2 = 0u;
    int m2 = m1;
    bool two = false, ok = true;
    if (m1 != mH) {  // second transition
        lo = p1; hi = Hb; mhi = mH;
        while (hi - lo > 1u) {
            unsigned int mid = lo + ((hi - lo) >> 1);
            int mm = predmask16(__uint_as_float(mid), hh, TT);
            if (mm == m1) lo = mid; else { hi = mid; mhi = mm; }
        }
        p2 = hi;
        m2 = mhi;
        two = true;
        ok = (m2 == mH);  // else >=3 transitions
    }
    if (ok) {
        int idx = atomicAdd((int*)&ws[W_NSIDE], 1);
        if (idx < NSIDE_MAX) {
            const unsigned int o1 = p1 - Lb;                   // 1..9215
            const unsigned int o2 = two ? (p2 - Lb) : 0xFFFFu; // sentinel > any off
            ws[W_SIDE + 4 * idx + 0] = (o2 << 16) | o1;
            ws[W_SIDE + 4 * idx + 1] = valbits(mL, dd);
            ws[W_SIDE + 4 * idx + 2] = valbits(m1, dd);
            ws[W_SIDE + 4 * idx + 3] = valbits(m2, dd);
            ws[W_LUT + u] = 0x7F800000u | (unsigned int)idx;
        } else {
            ws[W_LUT + u] = SCANTAG;
        }
    } else {
        ws[W_LUT + u] = SCANTAG;
    }
}

// ---------------------------------------------------------------- K2: apply
__device__ __forceinline__ float lut_elem(float xe,
                                          const unsigned int* __restrict__ lutS,
                                          const uint4* __restrict__ sideS,
                                          unsigned int lo_e, unsigned int hi_e,
                                          const float* __restrict__ hh,
                                          const float* __restrict__ dd,
                                          const float* __restrict__ TT) {
    const unsigned int u = __float_as_uint(xe);
    const unsigned int sb = u & 0x80000000u;
    const unsigned int ab = u & 0x7FFFFFFFu;
    unsigned int t = ab - BIN_B0;                    // wraps if ab < B0
    t = (t > BIN_RANGE - 1u) ? (BIN_RANGE - 1u) : t; // clamp wrap / high
    const unsigned int bin = ((t >> 10) * 58255u) >> 19;  // exact floor(/9216)
    unsigned int eb = lutS[bin];
    eb = (ab < BIN_B0) ? lo_e : eb;
    eb = (ab >= BIN_B1) ? hi_e : eb;
    if (__builtin_expect((eb & 0x7F800000u) == 0x7F800000u, 0)) {
        if (eb != SCANTAG) {
            const uint4 e = sideS[eb & 0x3FFu];
            const unsigned int off = ab - (BIN_B0 + bin * BIN_STEP);
            const unsigned int o1 = e.x & 0xFFFFu;
            const unsigned int o2 = e.x >> 16;
            const unsigned int j = (off >= o1 ? 1u : 0u) + (off >= o2 ? 1u : 0u);
            unsigned int v = (j == 0u) ? e.y : ((j == 1u) ? e.z : e.w);
            eb = v;
        } else {
            eb = __float_as_uint(scan_exact(ab, hh, dd, TT));  // cold
        }
    }
    const float r = __uint_as_float(eb ^ sb);
    return (xe == 0.0f) ? 0.0f : r;
}

__global__ __launch_bounds__(256) void snn_apply(
    const float* __restrict__ x, const float* __restrict__ h,
    const float* __restrict__ d, const float* __restrict__ T,
    float* __restrict__ out, const unsigned int* __restrict__ ws,
    int n8, int n4, int n) {
    __shared__ unsigned int lutS[NBIN];      // 16 KB
    __shared__ uint4 sideS[NSIDE_MAX];       // 8 KB
    const int tid = threadIdx.x;

    float hh[16], dd[16], TT[16];  // wave-uniform; cold path only
#pragma unroll
    for (int k = 0; k < 16; ++k) { hh[k] = h[k]; dd[k] = d[k]; TT[k] = T[k]; }

    for (int i = tid; i < NBIN; i += 256) lutS[i] = ws[W_LUT + i];
    const uint4* wside = reinterpret_cast<const uint4*>(ws + W_SIDE);
    for (int i = tid; i < NSIDE_MAX; i += 256) sideS[i] = wside[i];
    const unsigned int lo_e = ws[W_LO];
    const unsigned int hi_e = ws[W_HI];
    __syncthreads();

    const float4* __restrict__ x4 = reinterpret_cast<const float4*>(x);
    float4* __restrict__ o4 = reinterpret_cast<float4*>(out);
    const int gtid = blockIdx.x * blockDim.x + tid;
    const int nt = gridDim.x * blockDim.x;

#define APPLY4(vv)                                                             \
    {                                                                          \
        float4 ov;                                                             \
        ov.x = lut_elem(vv.x, lutS, sideS, lo_e, hi_e, hh, dd, TT);            \
        ov.y = lut_elem(vv.y, lutS, sideS, lo_e, hi_e, hh, dd, TT);            \
        ov.z = lut_elem(vv.z, lutS, sideS, lo_e, hi_e, hh, dd, TT);            \
        ov.w = lut_elem(vv.w, lutS, sideS, lo_e, hi_e, hh, dd, TT);            \
        vv = ov;                                                               \
    }

    int i = gtid;  // unit = pair of adjacent float4 (R4 skeleton)
    if (i < n8) {
        float4 ca = x4[2 * i], cb = x4[2 * i + 1];
        int nx = i + nt;
        while (nx < n8) {
            float4 pa = x4[2 * nx], pb = x4[2 * nx + 1];
            APPLY4(ca); APPLY4(cb);
            o4[2 * i] = ca; o4[2 * i + 1] = cb;
            ca = pa; cb = pb;
            i = nx; nx += nt;
        }
        APPLY4(ca); APPLY4(cb);
        o4[2 * i] = ca; o4[2 * i + 1] = cb;
    }
    for (int j = n8 * 2 + gtid; j < n4; j += nt) {
        float4 v = x4[j];
        APPLY4(v);
        o4[j] = v;
    }
    for (int j = n4 * 4 + gtid; j < n; j += nt)
        out[j] = lut_elem(x[j], lutS, sideS, lo_e, hi_e, hh, dd, TT);
#undef APPLY4
}

// -------------------------------------------- direct fallback (ws too small)
__global__ __launch_bounds__(256) void snn_direct(
    const float* __restrict__ x, const float* __restrict__ h,
    const float* __restrict__ d, const float* __restrict__ T,
    float* __restrict__ out, int n4, int n) {
    float hh[16], dd[16], TT[16];
#pragma unroll
    for (int k = 0; k < 16; ++k) { hh[k] = h[k]; dd[k] = d[k]; TT[k] = T[k]; }
    const float4* __restrict__ x4 = reinterpret_cast<const float4*>(x);
    float4* __restrict__ o4 = reinterpret_cast<float4*>(out);
    const int gtid = blockIdx.x * blockDim.x + threadIdx.x;
    const int nt = gridDim.x * blockDim.x;
    for (int i = gtid; i < n4; i += nt) {
        float4 v = x4[i], ov;
        float* pi = &v.x;
        float* po = &ov.x;
#pragma unroll
        for (int e = 0; e < 4; ++e) {
            float xe = pi[e];
            float acc = scan_exact(__float_as_uint(xe) & 0x7FFFFFFFu, hh, dd, TT);
            unsigned int rb =
                __float_as_uint(acc) ^ (__float_as_uint(xe) & 0x80000000u);
            po[e] = (xe == 0.0f) ? 0.0f : __uint_as_float(rb);
        }
        o4[i] = ov;
    }
    for (int j = n4 * 4 + gtid; j < n; j += nt) {
        float xe = x[j];
        float acc = scan_exact(__float_as_uint(xe) & 0x7FFFFFFFu, hh, dd, TT);
        unsigned int rb = __float_as_uint(acc) ^ (__float_as_uint(xe) & 0x80000000u);
        out[j] = (xe == 0.0f) ? 0.0f : __uint_as_float(rb);
    }
}

extern "C" void kernel_launch(void* const* d_in, const int* in_sizes, int n_in,
                              void* d_out, int out_size, void* d_ws, size_t ws_size,
                              hipStream_t stream) {
    const float* x = (const float*)d_in[0];
    const float* h = (const float*)d_in[1];
    const float* d = (const float*)d_in[2];
    const float* T = (const float*)d_in[3];
    float* out = (float*)d_out;

    const int n = in_sizes[0];
    const int n4 = n / 4;
    const int n8 = n / 8;

    if (ws_size < (size_t)WS_WORDS * 4) {
        int grid = 2048;
        const int needed = (n4 + 255) / 256;
        if (grid > needed) grid = needed > 0 ? needed : 1;
        snn_direct<<<grid, 256, 0, stream>>>(x, h, d, T, out, n4, n);
        return;
    }

    unsigned int* ws = (unsigned int*)d_ws;
    hipMemsetAsync(ws + W_NSIDE, 0, 4, stream);  // side-entry counter

    snn_build<<<(NBIN + 2 + 255) / 256, 256, 0, stream>>>(h, d, T, ws);

    // 24.6 KB LDS/block -> 6 blocks/CU -> 1536 blocks fills the chip.
    int grid = 1536;
    const int needed = (n8 + 255) / 256;
    if (grid > needed) grid = needed > 0 ? needed : 1;
    snn_apply<<<grid, 256, 0, stream>>>(x, h, d, T, out, ws, n8, n4, n);
}